// Round 5
// baseline (6547.485 us; speedup 1.0000x reference)
//
#include <hip/hip_runtime.h>

#define KK 25
#define KRR 19
#define NH 4
#define GG 100
#define FFH 128

__device__ __constant__ int c_l_per_k[25] = {0, 1,1,1, 2,2,2,2,2,
                                             3,3,3,3,3,3,3,
                                             4,4,4,4,4,4,4,4,4};

__device__ __forceinline__ float siluf(float x) { return x / (1.0f + expf(-x)); }
__device__ __forceinline__ float sigmf(float x) { return 1.0f / (1.0f + expf(-x)); }

// ---- k_scale: per-node RMS scale (f32) ----
__global__ void k_scale(const float* __restrict__ xf, float* __restrict__ scale) {
    int n = blockIdx.x, t = threadIdx.x;
    __shared__ float red[256];
    const float* xp = xf + (size_t)n * 1600;
    float ss = 0.f;
    for (int i = t; i < 1600; i += 256) { float v = xp[i]; ss += v * v; }
    red[t] = ss; __syncthreads();
    for (int s = 128; s > 0; s >>= 1) { if (t < s) red[t] += red[t + s]; __syncthreads(); }
    if (t == 0) scale[n] = rsqrtf(red[0] / 1600.0f + 1e-6f);
}

// ---- k_edge_logits: edge MLP + attention logits (normed x on the fly) ----
__global__ __launch_bounds__(128) void k_edge_logits(
        const float* __restrict__ edist, const float* __restrict__ emb_s,
        const float* __restrict__ emb_r, const float* __restrict__ We1,
        const float* __restrict__ We2, const float* __restrict__ Wso2,
        const float* __restrict__ Wa, const float* __restrict__ va,
        const float* __restrict__ wigner, const float* __restrict__ xf,
        const float* __restrict__ g1, const float* __restrict__ scale,
        const int* __restrict__ species, const int* __restrict__ senders,
        const int* __restrict__ receivers, float* __restrict__ logits) {
    int e = blockIdx.x, t = threadIdx.x;
    __shared__ float efin[128], h1[128], efs[64], xr0[128], msg0[64], ared[128];
    int s = senders[e], r = receivers[e];
    if (t < 64)       efin[t] = edist[(size_t)e * 64 + t];
    else if (t < 96)  efin[t] = emb_s[species[s] * 32 + (t - 64)];
    else              efin[t] = emb_r[species[r] * 32 + (t - 96)];
    {   // xr row 0 on the fly
        int c = t & 63;
        int node = (t < 64) ? s : r;
        float sc = scale[node];
        const float* xb = xf + (size_t)node * 1600;
        float a = 0.f;
        for (int k = 0; k < KK; ++k)
            a += wigner[(size_t)e * 475 + k] * xb[k * 64 + c] * g1[c_l_per_k[k] * 64 + c];
        xr0[t] = a * sc;
    }
    __syncthreads();
    {
        float a = 0.f;
        for (int c = 0; c < 128; ++c) a += efin[c] * We1[c * 128 + t];
        h1[t] = siluf(a);
    }
    __syncthreads();
    if (t < 64) {
        float a = 0.f;
        for (int c = 0; c < 128; ++c) a += h1[c] * We2[c * 64 + t];
        efs[t] = siluf(a);
    }
    __syncthreads();
    if (t < 64) {
        float a = 0.f;
        for (int c = 0; c < 128; ++c) a += xr0[c] * Wso2[c * 64 + t];
        a *= efs[t];
        msg0[t] = a * sigmf(a);
    }
    __syncthreads();
    {
        float a = 0.f;
        for (int d = 0; d < 64; ++d) a += msg0[d] * Wa[d * 128 + t];
        float av = (a > 0.f) ? a : 0.2f * a;
        ared[t] = av * va[t];
    }
    __syncthreads();
    if (t < NH) {
        float sum = 0.f;
        for (int a = 0; a < 32; ++a) sum += ared[t * 32 + a];
        logits[(size_t)e * NH + t] = sum;
    }
}

// ---- CSR build ----
__global__ void k_count(const int* __restrict__ receivers, int* __restrict__ counts, int E) {
    int e = blockIdx.x * blockDim.x + threadIdx.x;
    if (e < E) atomicAdd(&counts[receivers[e]], 1);
}

__global__ void k_scan(int* __restrict__ counts, int* __restrict__ offsets, int n) {
    __shared__ int buf[256];
    __shared__ int base_s;
    int t = threadIdx.x;
    if (t == 0) base_s = 0;
    __syncthreads();
    for (int start = 0; start < n; start += 256) {
        int idx = start + t;
        int v = (idx < n) ? counts[idx] : 0;
        buf[t] = v; __syncthreads();
        for (int o = 1; o < 256; o <<= 1) {
            int x = (t >= o) ? buf[t - o] : 0;
            __syncthreads();
            buf[t] += x;
            __syncthreads();
        }
        int incl = buf[t];
        int b = base_s;
        if (idx < n) { offsets[idx] = b + incl - v; counts[idx] = 0; }
        __syncthreads();
        if (t == 0) base_s = b + buf[255];
        __syncthreads();
    }
    if (t == 0) offsets[n] = base_s;
}

__global__ void k_fill(const int* __restrict__ receivers, const int* __restrict__ offsets,
                       int* __restrict__ cursors, int* __restrict__ edge_ids, int E) {
    int e = blockIdx.x * blockDim.x + threadIdx.x;
    if (e >= E) return;
    int r = receivers[e];
    int pos = atomicAdd(&cursors[r], 1);
    edge_ids[offsets[r] + pos] = e;
}

// ---- k_node: gather edges, attention, residual+norm2+FFN fused ----
#define P_XRCV 0
#define P_ACC  1600
#define P_A    3200
#define A_XS    0
#define A_WIG   1600
#define A_WINV  2075
#define A_XR    2550
#define A_MSG   4982
#define A_V2    6198
#define A_VF    7414
#define A_EFIN  9014
#define A_H1    9142
#define A_EFS   9270
#define A_SIG   9334
#define B_OG    0
#define B_XN2   6400
#define B_XG    8000
#define B_HS    8256
#define B_RED   8768
#define P_STAT 12598
#define POOL_SZ 12610

__global__ __launch_bounds__(256) void k_node(
        const float* __restrict__ xf, const float* __restrict__ wigner,
        const float* __restrict__ wigner_inv, const float* __restrict__ edist,
        const float* __restrict__ emb_s, const float* __restrict__ emb_r,
        const float* __restrict__ We1, const float* __restrict__ We2,
        const float* __restrict__ Wso2, const float* __restrict__ Wv,
        const float* __restrict__ Wo, const float* __restrict__ g1,
        const float* __restrict__ g2, const float* __restrict__ to_grid,
        const float* __restrict__ from_grid, const float* __restrict__ Wf1,
        const float* __restrict__ Wf2, const float* __restrict__ scale,
        const float* __restrict__ logits, const int* __restrict__ species,
        const int* __restrict__ senders, const int* __restrict__ offsets,
        const int* __restrict__ edge_ids, float* __restrict__ out) {
    __shared__ float P[POOL_SZ];
    int n = blockIdx.x, t = threadIdx.x;
    int off = offsets[n];
    int deg = offsets[n + 1] - off;
    float scn = scale[n];
    int spec_n = species[n];
    // receiver normed feats + zero acc
    for (int i = t; i < 1600; i += 256) {
        int k = i >> 6, c = i & 63;
        P[P_XRCV + i] = xf[(size_t)n * 1600 + i] * scn * g1[c_l_per_k[k] * 64 + c];
        P[P_ACC + i] = 0.f;
    }
    // local softmax stats (m, den) per head
    if (t < NH) {
        float m = -1e30f;
        for (int i = 0; i < deg; ++i)
            m = fmaxf(m, logits[(size_t)edge_ids[off + i] * NH + t]);
        float s = 0.f;
        for (int i = 0; i < deg; ++i)
            s += expf(logits[(size_t)edge_ids[off + i] * NH + t] - m);
        P[P_STAT + t] = m;
        P[P_STAT + 4 + t] = s;
    }
    __syncthreads();
    for (int ii = 0; ii < deg; ++ii) {
        int e = edge_ids[off + ii];
        int s = senders[e];
        float scs = scale[s];
        // stage 1: loads (+ alpha)
        for (int i = t; i < 1600; i += 256) {
            int k = i >> 6, c = i & 63;
            P[P_A + A_XS + i] = xf[(size_t)s * 1600 + i] * scs * g1[c_l_per_k[k] * 64 + c];
        }
        for (int i = t; i < 475; i += 256) P[P_A + A_WIG + i]  = wigner[(size_t)e * 475 + i];
        for (int i = t; i < 475; i += 256) P[P_A + A_WINV + i] = wigner_inv[(size_t)e * 475 + i];
        if (t < 64)       P[P_A + A_EFIN + t] = edist[(size_t)e * 64 + t];
        else if (t < 96)  P[P_A + A_EFIN + t] = emb_s[species[s] * 32 + (t - 64)];
        else if (t < 128) P[P_A + A_EFIN + t] = emb_r[spec_n * 32 + (t - 96)];
        if (t >= 128 && t < 128 + NH) {
            int h = t - 128;
            float ex = expf(logits[(size_t)e * NH + h] - P[P_STAT + h]);
            P[P_STAT + 8 + h] = ex / (P[P_STAT + 4 + h] + 1e-9f);
        }
        __syncthreads();
        // stage 2: xr = wig @ [xs|xrcv]; h1 = silu(efin@We1)
        for (int i = t; i < KRR * 128; i += 256) {
            int r_ = i >> 7, c = i & 127;
            const float* xe = (c < 64) ? &P[P_A + A_XS] : &P[P_XRCV];
            int cc = c & 63;
            float a = 0.f;
            for (int k = 0; k < KK; ++k) a += P[P_A + A_WIG + r_ * 25 + k] * xe[k * 64 + cc];
            P[P_A + A_XR + i] = a;
        }
        if (t < 128) {
            float a = 0.f;
            for (int c = 0; c < 128; ++c) a += P[P_A + A_EFIN + c] * We1[c * 128 + t];
            P[P_A + A_H1 + t] = siluf(a);
        }
        __syncthreads();
        // stage 3: efs
        if (t < 64) {
            float a = 0.f;
            for (int c = 0; c < 128; ++c) a += P[P_A + A_H1 + c] * We2[c * 64 + t];
            P[P_A + A_EFS + t] = siluf(a);
        }
        __syncthreads();
        // stage 4: msg = (xr @ Wso2) * efs
        for (int i = t; i < KRR * 64; i += 256) {
            int r_ = i >> 6, d = i & 63;
            float a = 0.f;
            for (int c = 0; c < 128; ++c) a += P[P_A + A_XR + r_ * 128 + c] * Wso2[c * 64 + d];
            P[P_A + A_MSG + i] = a * P[P_A + A_EFS + d];
        }
        __syncthreads();
        // stage 5: gate
        if (t < 64) P[P_A + A_SIG + t] = sigmf(P[P_A + A_MSG + t]);
        __syncthreads();
        for (int i = t; i < KRR * 64; i += 256) P[P_A + A_MSG + i] *= P[P_A + A_SIG + (i & 63)];
        __syncthreads();
        // stage 6: v2 = (msg @ Wv) * alpha
        for (int i = t; i < KRR * 64; i += 256) {
            int r_ = i >> 6, d2 = i & 63;
            float a = 0.f;
            for (int d = 0; d < 64; ++d) a += P[P_A + A_MSG + r_ * 64 + d] * Wv[d * 64 + d2];
            P[P_A + A_V2 + i] = a * P[P_STAT + 8 + (d2 >> 4)];
        }
        __syncthreads();
        // stage 7: vf = winv @ v2
        for (int i = t; i < 1600; i += 256) {
            int k = i >> 6, d2 = i & 63;
            float a = 0.f;
            for (int r_ = 0; r_ < KRR; ++r_) a += P[P_A + A_WINV + k * KRR + r_] * P[P_A + A_V2 + r_ * 64 + d2];
            P[P_A + A_VF + i] = a;
        }
        __syncthreads();
        // stage 8: acc += vf @ Wo
        for (int i = t; i < 1600; i += 256) {
            int k = i >> 6, c = i & 63;
            float a = 0.f;
            for (int d = 0; d < 64; ++d) a += P[P_A + A_VF + k * 64 + d] * Wo[d * 64 + c];
            P[P_ACC + i] += a;
        }
        __syncthreads();
    }
    // ---- phase B: residual + norm2 + grid FFN ----
    float ss = 0.f;
    for (int i = t; i < 1600; i += 256) {
        float v = P[P_ACC + i] + xf[(size_t)n * 1600 + i];
        P[P_ACC + i] = v;
        ss += v * v;
    }
    P[P_A + B_RED + t] = ss; __syncthreads();
    for (int s = 128; s > 0; s >>= 1) {
        if (t < s) P[P_A + B_RED + t] += P[P_A + B_RED + t + s];
        __syncthreads();
    }
    float sc2 = rsqrtf(P[P_A + B_RED] / 1600.0f + 1e-6f);
    for (int i = t; i < 1600; i += 256) {
        int k = i >> 6, c = i & 63;
        P[P_A + B_XN2 + i] = P[P_ACC + i] * sc2 * g2[c_l_per_k[k] * 64 + c];
    }
    __syncthreads();
    int grp = t >> 6, col = t & 63;
    for (int g0 = 0; g0 < GG; g0 += 4) {
        int g = g0 + grp;
        {
            float a = 0.f;
            for (int k = 0; k < KK; ++k) a += to_grid[g * KK + k] * P[P_A + B_XN2 + k * 64 + col];
            P[P_A + B_XG + grp * 64 + col] = a;
        }
        __syncthreads();
        for (int jj = 0; jj < 2; ++jj) {
            int j = col + 64 * jj;
            float a = 0.f;
            for (int c = 0; c < 64; ++c) a += P[P_A + B_XG + grp * 64 + c] * Wf1[c * FFH + j];
            P[P_A + B_HS + grp * FFH + j] = siluf(a);
        }
        __syncthreads();
        {
            float a = 0.f;
            for (int j = 0; j < FFH; ++j) a += P[P_A + B_HS + grp * FFH + j] * Wf2[j * 64 + col];
            P[P_A + B_OG + g * 64 + col] = a;
        }
        __syncthreads();
    }
    for (int i = t; i < 1600; i += 256) {
        int k = i >> 6, c = i & 63;
        float a = P[P_ACC + i];
        for (int g = 0; g < GG; ++g) a += from_grid[k * GG + g] * P[P_A + B_OG + g * 64 + c];
        out[(size_t)n * 1600 + i] = a;
    }
}

extern "C" void kernel_launch(void* const* d_in, const int* in_sizes, int n_in,
                              void* d_out, int out_size, void* d_ws, size_t ws_size,
                              hipStream_t stream) {
    const float* node_feats     = (const float*)d_in[0];
    const float* edge_distances = (const float*)d_in[1];
    const float* wigner         = (const float*)d_in[2];
    const float* wigner_inv     = (const float*)d_in[3];
    const int*   node_species   = (const int*)  d_in[4];
    const int*   senders        = (const int*)  d_in[5];
    const int*   receivers      = (const int*)  d_in[6];
    const float* g1             = (const float*)d_in[7];
    const float* g2             = (const float*)d_in[8];
    const float* emb_s          = (const float*)d_in[9];
    const float* emb_r          = (const float*)d_in[10];
    const float* We1            = (const float*)d_in[11];
    const float* We2            = (const float*)d_in[12];
    const float* Wso2           = (const float*)d_in[13];
    const float* Wa             = (const float*)d_in[14];
    const float* va             = (const float*)d_in[15];
    const float* Wv             = (const float*)d_in[16];
    const float* Wo             = (const float*)d_in[17];
    const float* to_grid        = (const float*)d_in[18];
    const float* from_grid      = (const float*)d_in[19];
    const float* Wf1            = (const float*)d_in[20];
    const float* Wf2            = (const float*)d_in[21];

    const int N = in_sizes[4];
    const int E = in_sizes[5];

    char* ws = (char*)d_ws;
    size_t o = 0;
    float* scale    = (float*)(ws + o); o += (size_t)N * 4;
    int*   counts   = (int*)  (ws + o); o += (size_t)N * 4;
    int*   offsets  = (int*)  (ws + o); o += (size_t)(N + 1) * 4;
    int*   edge_ids = (int*)  (ws + o); o += (size_t)E * 4;
    float* logits   = (float*)(ws + o); o += (size_t)E * NH * 4;
    // total ws use ~720 KB

    hipMemsetAsync(counts, 0, (size_t)N * 4, stream);

    k_scale<<<N, 256, 0, stream>>>(node_feats, scale);
    k_edge_logits<<<E, 128, 0, stream>>>(edge_distances, emb_s, emb_r, We1, We2, Wso2,
                                         Wa, va, wigner, node_feats, g1, scale,
                                         node_species, senders, receivers, logits);
    k_count<<<(E + 255) / 256, 256, 0, stream>>>(receivers, counts, E);
    k_scan<<<1, 256, 0, stream>>>(counts, offsets, N);
    k_fill<<<(E + 255) / 256, 256, 0, stream>>>(receivers, offsets, counts, edge_ids, E);
    k_node<<<N, 256, 0, stream>>>(node_feats, wigner, wigner_inv, edge_distances,
                                  emb_s, emb_r, We1, We2, Wso2, Wv, Wo, g1, g2,
                                  to_grid, from_grid, Wf1, Wf2, scale, logits,
                                  node_species, senders, offsets, edge_ids,
                                  (float*)d_out);
}